// Round 8
// baseline (264.027 us; speedup 1.0000x reference)
//
#include <hip/hip_runtime.h>
#include <hip/hip_bf16.h>

// SrnmSpmm: out[b,s,n] = sum_k x[b,s,keep[k]] * values[n,k] + bias[n]
// keep: cols {8i, 8i+2} of D_IN=4096 -> K=1024. M = B*S = 16384, N = 4096.
//
// R8: register-double-buffered fragment pipeline: phase p = {vmcnt; BAR;
// STAGE(slot p+7); ds_reads for phase p+1 into the OTHER frag set; MFMA(p)}.
// MFMA issues right off the barrier (regs ready) and overlaps its own wave's
// ds_reads -> phase time = max(LDS, MFMA) not sum. Slot = quarter K-tile
// (A or B half-K panel, 16 KiB); 8-region LDS ring; 1 slot staged/phase,
// 7-phase lead; vmcnt(8) steady (= 4 newest slots in flight), vmcnt(63) for
// 4 post-epilogue phases. Persistent remap: per XCD per round 4 A x 8 B
// panels (L2 working set 6 MB).

#define M_TOTAL 16384
#define DIN     4096
#define KDIM    1024
#define NDIM    4096

typedef unsigned short u16;
typedef unsigned int   u32;
typedef __bf16 bf16x8 __attribute__((ext_vector_type(8)));
typedef float  f32x4  __attribute__((ext_vector_type(4)));

typedef const void __attribute__((address_space(1)))* gp_t;
typedef void __attribute__((address_space(3)))*       lp_t;

__device__ __forceinline__ u16 f2bf(float f) {
    u32 u = __float_as_uint(f);
    u += 0x7FFFu + ((u >> 16) & 1u);   // round-to-nearest-even
    return (u16)(u >> 16);
}
__device__ __forceinline__ u32 pack2(float a, float b) {
    return (u32)f2bf(a) | ((u32)f2bf(b) << 16);
}

// Pass 1: blocks [0,4096): compact x — each lane owns one 64B line (2 x
// 8-block): f32x4 @ +0 and @ +32B -> uint2 (kept cols 0,2). NT loads.
// Blocks [4096,6144): cast values, 8 floats/lane -> uint4. NT loads.
__global__ void prep_kernel(const float* __restrict__ x, uint2* __restrict__ xg2,
                            const float* __restrict__ vals, uint4* __restrict__ vb4) {
    const int tid = threadIdx.x;
    if (blockIdx.x < 4096) {
        int i = blockIdx.x * 256 + tid;
        const int stride = 4096 * 256;
#pragma unroll
        for (int it = 0; it < 4; ++it, i += stride) {
            const f32x4* p = (const f32x4*)(x + (size_t)i * 16);
            f32x4 f0 = __builtin_nontemporal_load(p);
            f32x4 f1 = __builtin_nontemporal_load(p + 2);
            xg2[i] = make_uint2(pack2(f0.x, f0.z), pack2(f1.x, f1.z));
        }
    } else {
        const int i = (blockIdx.x - 4096) * 256 + tid;
        const f32x4* p = (const f32x4*)(vals + (size_t)i * 8);
        f32x4 a = __builtin_nontemporal_load(p);
        f32x4 b = __builtin_nontemporal_load(p + 1);
        vb4[i] = make_uint4(pack2(a.x, a.y), pack2(a.z, a.w),
                            pack2(b.x, b.y), pack2(b.z, b.w));
    }
}

// Slot S (quarter K-tile): t=S>>2, kh=(S>>1)&1, isB=S&1, d=t&1.
// A slot region @ (d*2+kh)*16K; B slot region @ 64K + (d*2+kh)*16K.
// Phase p: MFMA(p): t=p>>2, ph=p&3 (mh = ph&1, kh = ph>>1).
// Reads during phase p are for phase p+1. af sets toggle per phase
// (set = (p+1)&1 written, p&1 consumed); bfr sets toggle per K-half.

#define LDSA(d, kh) (((d) * 2 + (kh)) * 16384)
#define LDSB(d, kh) (65536 + ((d) * 2 + (kh)) * 16384)

#define LA(d, kh, mh, AF) { _Pragma("unroll") \
    for (int m_ = 0; m_ < 4; ++m_) \
        AF[m_] = *(const bf16x8*)(lds + LDSA(d, kh) + (wr * 8 + (mh) * 4 + m_) * 1024 + fl_off); }

#define LB(d, kh, BF) { _Pragma("unroll") \
    for (int n_ = 0; n_ < 4; ++n_) \
        BF[n_] = *(const bf16x8*)(lds + LDSB(d, kh) + (wc * 4 + n_) * 1024 + fl_off); }

#define MFMA16(mh, AF, BF) { \
    __builtin_amdgcn_s_setprio(1); \
    _Pragma("unroll") for (int m_ = 0; m_ < 4; ++m_) \
    _Pragma("unroll") for (int n_ = 0; n_ < 4; ++n_) \
        acc[(mh) * 4 + m_][n_] = __builtin_amdgcn_mfma_f32_16x16x32_bf16( \
            AF[m_], BF[n_], acc[(mh) * 4 + m_][n_], 0, 0, 0); \
    __builtin_amdgcn_s_setprio(0); }

#define BAR() __builtin_amdgcn_s_barrier()
#define VM8  asm volatile("s_waitcnt vmcnt(8)"  ::: "memory");
#define VM63 asm volatile("s_waitcnt vmcnt(63)" ::: "memory");

// Phase: {wait; barrier; stage slot; reads for next phase; MFMA this phase}
#define PHASE(W, S_, RD, MH, AF, BF) { W BAR(); STAGE(S_); RD MFMA16(MH, AF, BF); }

// 8 phases = K-tile pair (d=0 then d=1). S0 = slot staged at first phase.
#define ITER2(W1, W2, S0) { \
  PHASE(W1, (S0)+0, LA(0,0,1,afB),                0, afA, bfrA) \
  PHASE(W1, (S0)+1, LB(0,1,bfrB) LA(0,1,0,afA),   1, afB, bfrA) \
  PHASE(W1, (S0)+2, LA(0,1,1,afB),                0, afA, bfrB) \
  PHASE(W1, (S0)+3, LB(1,0,bfrA) LA(1,0,0,afA),   1, afB, bfrB) \
  PHASE(W2, (S0)+4, LA(1,0,1,afB),                0, afA, bfrA) \
  PHASE(W2, (S0)+5, LB(1,1,bfrB) LA(1,1,0,afA),   1, afB, bfrA) \
  PHASE(W2, (S0)+6, LA(1,1,1,afB),                0, afA, bfrB) \
  PHASE(W2, (S0)+7, LB(0,0,bfrA) LA(0,0,0,afA),   1, afB, bfrB) }

__global__ __launch_bounds__(512, 2) void gemm_kernel(
    const u16* __restrict__ A, const u16* __restrict__ Bv,
    const float* __restrict__ bias, float* __restrict__ C)
{
    __shared__ __align__(1024) char lds[131072];

    const int tid  = threadIdx.x;
    const int lane = tid & 63;
    const int wid  = tid >> 6;
    const int wr   = wid >> 2;      // 0..1
    const int wc   = wid & 3;       // 0..3
    const int lrow = lane & 15;
    const int lg   = lane >> 4;     // 0..3

    // Persistent remap: XCD c = bb&7; idx = bb>>3: im = idx&3, in_ = idx>>2.
    // Round r: btm = c*8 + im*2 + (r>>1), btn = in_*2 + (r&1).
    // Per XCD per round: 4 unique A panels + 8 unique B panels (6 MB).
    const int bb  = blockIdx.x;
    const int c   = bb & 7;
    const int idx = bb >> 3;
    const int im  = idx & 3;
    const int in_ = idx >> 2;

    // Staging source (pre-swizzled global addr; LDS dest linear).
    const int st_r0 = wid * 16 + (lane >> 2);
    const int st_ck = ((lane & 3) * 8) ^ ((lane & 32) >> 1);
    const int dst0 = tid * 16;

    // Fragment ds_read offset within a 16KiB region (subtiled + swizzled).
    const int fl_off = lrow * 64 + ((lg * 16) ^ (((lrow >> 3) & 1) << 5));

    auto PA = [&](int r) {
        return A + (size_t)((c * 8 + im * 2 + (r >> 1)) * 256 + st_r0) * KDIM + st_ck;
    };
    auto PB = [&](int r) {
        return Bv + (size_t)((in_ * 2 + (r & 1)) * 256 + st_r0) * KDIM + st_ck;
    };

    const u16* curA = PA(0);
    const u16* curB = PB(0);
    const u16* nxtA = curA;
    const u16* nxtB = curB;

    // Stage slot s (runtime): s in [0,71); s>=64 -> next round's panels.
    auto STAGE = [&](int s) {
        const int ss = s & 63;
        const u16* sa = (s >= 64) ? nxtA : curA;
        const u16* sb = (s >= 64) ? nxtB : curB;
        const int tt = ss >> 2, kh = (ss >> 1) & 1, isB = ss & 1, d = tt & 1;
        const int ko = tt * 64 + kh * 32;
        const u16* src = isB ? sb : sa;
        const int base = isB * 65536 + (d * 2 + kh) * 16384;
        __builtin_amdgcn_global_load_lds((gp_t)(src + ko),
            (lp_t)(lds + base + dst0), 16, 0, 0);
        __builtin_amdgcn_global_load_lds((gp_t)(src + 128 * KDIM + ko),
            (lp_t)(lds + base + 8192 + dst0), 16, 0, 0);
    };

    f32x4 acc[8][4] = {};
    bf16x8 afA[4], afB[4], bfrA[4], bfrB[4];

    // Prologue: stage slots 0..6; preload phase-0 fragments (slots 0,1).
    STAGE(0); STAGE(1); STAGE(2); STAGE(3); STAGE(4); STAGE(5); STAGE(6);
    asm volatile("s_waitcnt vmcnt(10)" ::: "memory");   // slots 0,1 landed
    BAR();
    LB(0, 0, bfrA) LA(0, 0, 0, afA)

#pragma unroll 1
    for (int r = 0; r < 4; ++r) {
        nxtA = (r < 3) ? PA(r + 1) : curA;
        nxtB = (r < 3) ? PB(r + 1) : curB;

        // First ITER2: post-epilogue rounds wait vmcnt(63) for phases 0..3
        // (their slots predate the 128 C-stores), vmcnt(8) from phase 4.
        if (r == 0) { ITER2(VM8, VM8, 7) }
        else        { ITER2(VM63, VM8, 7) }

#pragma unroll 1
        for (int u = 1; u < 8; ++u) {
            ITER2(VM8, VM8, 8 * u + 7)
        }

        // Epilogue tile r: NT stores. (Fragments for next round's phase 0
        // were loaded during the last phase above and stay live.)
        const int c_row0 = (c * 8 + im * 2 + (r >> 1)) * 256 + wr * 128 + lg * 4;
        const int c_col0 = (in_ * 2 + (r & 1)) * 256 + wc * 64 + lrow;
        float bvr[4];
#pragma unroll
        for (int n = 0; n < 4; ++n) bvr[n] = bias[c_col0 + n * 16];
#pragma unroll
        for (int mi = 0; mi < 8; ++mi) {
            const int row = c_row0 + (mi >> 2) * 64 + (mi & 3) * 16;
#pragma unroll
            for (int n = 0; n < 4; ++n) {
#pragma unroll
                for (int j = 0; j < 4; ++j)
                    __builtin_nontemporal_store(acc[mi][n][j] + bvr[n],
                        &C[(size_t)(row + j) * NDIM + c_col0 + n * 16]);
                acc[mi][n] = (f32x4){0.f, 0.f, 0.f, 0.f};
            }
        }
        curA = nxtA;
        curB = nxtB;
    }
}

extern "C" void kernel_launch(void* const* d_in, const int* in_sizes, int n_in,
                              void* d_out, int out_size, void* d_ws, size_t ws_size,
                              hipStream_t stream) {
    const float* x      = (const float*)d_in[0];
    const float* values = (const float*)d_in[1];
    const float* bias   = (const float*)d_in[2];
    float* out = (float*)d_out;

    // ws: xg bf16 [16384][1024] = 32 MB @ 0; values bf16 [4096][1024] @ 32 MB
    u16* xg = (u16*)d_ws;
    u16* vb = (u16*)((char*)d_ws + ((size_t)32 << 20));

    prep_kernel<<<6144, 256, 0, stream>>>(x, (uint2*)xg, values, (uint4*)vb);
    gemm_kernel<<<256, 512, 0, stream>>>(xg, vb, bias, out);
}

// Round 10
// 216.592 us; speedup vs baseline: 1.2190x; 1.2190x over previous
//
#include <hip/hip_runtime.h>
#include <hip/hip_bf16.h>

// SrnmSpmm: out[b,s,n] = sum_k x[b,s,keep[k]] * values[n,k] + bias[n]
// keep: cols {8i, 8i+2} of D_IN=4096 -> K=1024. M = B*S = 16384, N = 4096.
//
// R10: non-persistent 1024-block GEMM, 8-region LDS ring (8 x 16 KiB),
// 1 slot staged/phase with 7-slot lead, MINIMAL per-phase waits
// (vmcnt(10) when reading slots <= p+1, vmcnt(14) when reading slot p-1)
// so the pipeline never blocks on data needed in the future. Wait precedes
// a barrier that precedes the reads (all-waves landed guarantee — R9 fix).
// Swapped-operand MFMA -> each lane holds 4 consecutive C-cols -> float4
// coalesced C stores (32/wave vs 128 strided scalars).

#define M_TOTAL 16384
#define DIN     4096
#define KDIM    1024
#define NDIM    4096

typedef unsigned short u16;
typedef unsigned int   u32;
typedef __bf16 bf16x8 __attribute__((ext_vector_type(8)));
typedef float  f32x4  __attribute__((ext_vector_type(4)));

typedef const void __attribute__((address_space(1)))* gp_t;
typedef void __attribute__((address_space(3)))*       lp_t;

__device__ __forceinline__ u16 f2bf(float f) {
    u32 u = __float_as_uint(f);
    u += 0x7FFFu + ((u >> 16) & 1u);   // round-to-nearest-even
    return (u16)(u >> 16);
}
__device__ __forceinline__ u32 pack2(float a, float b) {
    return (u32)f2bf(a) | ((u32)f2bf(b) << 16);
}

// Pass 1: blocks [0,4096): compact x — each lane owns one 64B line (2 x
// 8-block): f32x4 @ +0 and @ +32B -> uint2 (kept cols 0,2). NT loads.
// Blocks [4096,6144): cast values, 8 floats/lane -> uint4. NT loads.
__global__ void prep_kernel(const float* __restrict__ x, uint2* __restrict__ xg2,
                            const float* __restrict__ vals, uint4* __restrict__ vb4) {
    const int tid = threadIdx.x;
    if (blockIdx.x < 4096) {
        int i = blockIdx.x * 256 + tid;
        const int stride = 4096 * 256;
#pragma unroll
        for (int it = 0; it < 4; ++it, i += stride) {
            const f32x4* p = (const f32x4*)(x + (size_t)i * 16);
            f32x4 f0 = __builtin_nontemporal_load(p);
            f32x4 f1 = __builtin_nontemporal_load(p + 2);
            xg2[i] = make_uint2(pack2(f0.x, f0.z), pack2(f1.x, f1.z));
        }
    } else {
        const int i = (blockIdx.x - 4096) * 256 + tid;
        const f32x4* p = (const f32x4*)(vals + (size_t)i * 8);
        f32x4 a = __builtin_nontemporal_load(p);
        f32x4 b = __builtin_nontemporal_load(p + 1);
        vb4[i] = make_uint4(pack2(a.x, a.y), pack2(a.z, a.w),
                            pack2(b.x, b.y), pack2(b.z, b.w));
    }
}

// ---------------- 256x256 bf16 GEMM, 8-slot ring, minimal waits ------------
// 512 threads = 8 waves (2M x 4N); wave tile 128x64. K-tile 64 = 2 K-halves.
// Slot s (quarter-K-tile panel, 16 KiB): t=s>>2, kh=(s>>1)&1, isB=s&1.
// Region = s&7 (16 KiB each): A regions {0,2,4,6}, B {1,3,5,7}; for K-tile t
// (d=t&1): A(d,kh) @ (d*4+2kh)*16K, B(d,kh) @ (d*4+2kh+1)*16K.
// Phase p=4t+q: q0 reads slots {p,p+1}, q1 reads {p-1}, q2 {p,p+1}, q3 {p-1}.
// Stage at phase p = slot p+7 (ring depth 8 => overwrites slot p-1's region,
// whose readers all completed before this phase's first barrier).
// Waits (before BAR1, exact instruction counts, 2 instr/slot):
//   q0/q2: issued <= p+6, need <= p+1  -> 5 slots out -> vmcnt(10)
//   q1/q3: issued <= p+6, need <= p-1  -> 7 slots out -> vmcnt(14)
// st_16x32 swizzle on global SOURCE (gload_lds dest linear) + ds_read addr.

#define LDSA(d, kh) (((d) * 4 + 2 * (kh)) * 16384)
#define LDSB(d, kh) (((d) * 4 + 2 * (kh) + 1) * 16384)

#define LOADA(d, kh, mh) { _Pragma("unroll") \
    for (int m_ = 0; m_ < 4; ++m_) \
        af[m_] = *(const bf16x8*)(lds + LDSA(d, kh) + (wr * 8 + (mh) * 4 + m_) * 1024 + fl_off); }

#define LOADB(d, kh) { _Pragma("unroll") \
    for (int n_ = 0; n_ < 4; ++n_) \
        bfr[n_] = *(const bf16x8*)(lds + LDSB(d, kh) + (wc * 4 + n_) * 1024 + fl_off); }

// Swapped operands: D = Bfrag x Afrag^T = C^T fragment; lane then holds
// C[row = lane&15 (+frag row)][cols = (lane>>4)*4 + 0..3] -> float4 stores.
#define MFMA16(mh) { \
    __builtin_amdgcn_s_setprio(1); \
    _Pragma("unroll") for (int m_ = 0; m_ < 4; ++m_) \
    _Pragma("unroll") for (int n_ = 0; n_ < 4; ++n_) \
        acc[(mh) * 4 + m_][n_] = __builtin_amdgcn_mfma_f32_16x16x32_bf16( \
            bfr[n_], af[m_], acc[(mh) * 4 + m_][n_], 0, 0, 0); \
    __builtin_amdgcn_s_setprio(0); }

#define BAR()  __builtin_amdgcn_s_barrier()
#define VM10() asm volatile("s_waitcnt vmcnt(10)" ::: "memory")
#define VM14() asm volatile("s_waitcnt vmcnt(14)" ::: "memory")

__global__ __launch_bounds__(512, 2) void gemm_kernel(
    const u16* __restrict__ A, const u16* __restrict__ Bv,
    const float* __restrict__ bias, float* __restrict__ C)
{
    __shared__ __align__(1024) char lds[131072];

    const int tid  = threadIdx.x;
    const int lane = tid & 63;
    const int wid  = tid >> 6;
    const int wr   = wid >> 2;      // 0..1
    const int wc   = wid & 3;       // 0..3
    const int lrow = lane & 15;
    const int lg   = lane >> 4;     // 0..3

    // XCD-chunked bijective map: XCD (b&7) owns btm slab {8x..8x+7}, all btn.
    const int b   = blockIdx.x;
    const int swz = (b & 7) * 128 + (b >> 3);
    const int btm = swz >> 4;       // 0..63
    const int btn = swz & 15;       // 0..15

    // Staging source (pre-swizzled global addr; LDS dest linear).
    const int st_r0 = wid * 16 + (lane >> 2);
    const int st_ck = ((lane & 3) * 8) ^ ((lane & 32) >> 1);
    const u16* Ap = A  + (size_t)(btm * 256 + st_r0) * KDIM + st_ck;
    const u16* Bp = Bv + (size_t)(btn * 256 + st_r0) * KDIM + st_ck;
    const int dst0 = tid * 16;

    // Fragment ds_read offset within a 16 KiB region (subtiled + swizzled).
    const int fl_off = lrow * 64 + ((lg * 16) ^ (((lrow >> 3) & 1) << 5));

    // Stage slot s; s>=64 -> dummy re-stage of slot s-8 (same region, same
    // data: harmless overwrite, keeps vmcnt instruction counts exact).
    auto STAGE = [&](int s) {
        const int ss = (s < 64) ? s : s - 8;
        const int tt = ss >> 2, kh = (ss >> 1) & 1, isB = ss & 1;
        const int ko = tt * 64 + kh * 32;
        const u16* src = isB ? Bp : Ap;
        const int base = (ss & 7) * 16384;
        __builtin_amdgcn_global_load_lds((gp_t)(src + ko),
            (lp_t)(lds + base + dst0), 16, 0, 0);
        __builtin_amdgcn_global_load_lds((gp_t)(src + 128 * KDIM + ko),
            (lp_t)(lds + base + 8192 + dst0), 16, 0, 0);
    };

    f32x4 acc[8][4] = {};
    bf16x8 af[4], bfr[4];

    // Prologue: stage slots 0..6 (7 slots, 14 instrs in flight).
    STAGE(0); STAGE(1); STAGE(2); STAGE(3); STAGE(4); STAGE(5); STAGE(6);

#pragma unroll 1
    for (int t = 0; t < 16; ++t) {
        const int d = t & 1;
        const int p = 4 * t;
        // q0: reads A(d,0) mh0 + B(d,0) = slots p, p+1
        VM10(); BAR(); LOADB(d, 0); LOADA(d, 0, 0); STAGE(p + 7);
        BAR(); MFMA16(0);
        // q1: reads A(d,0) mh1 = slot p-1's... (slot 4t)
        VM14(); BAR(); LOADA(d, 0, 1); STAGE(p + 8);
        BAR(); MFMA16(1);
        // q2: reads A(d,1) mh0 + B(d,1) = slots p+2, p+3
        VM10(); BAR(); LOADB(d, 1); LOADA(d, 1, 0); STAGE(p + 9);
        BAR(); MFMA16(0);
        // q3: reads A(d,1) mh1 = slot p+2
        VM14(); BAR(); LOADA(d, 1, 1); STAGE(p + 10);
        BAR(); MFMA16(1);
    }

    // Epilogue: bias + coalesced float4 stores (swapped-operand layout:
    // C-row = frag_row + lrow, C-cols = n*16 + lg*4 + {0..3}).
    const int c_row0 = btm * 256 + wr * 128 + lrow;
    const int c_col0 = btn * 256 + wc * 64 + lg * 4;
    f32x4 bvr[4];
#pragma unroll
    for (int n = 0; n < 4; ++n)
        bvr[n] = *(const f32x4*)&bias[c_col0 + n * 16];
#pragma unroll
    for (int mi = 0; mi < 8; ++mi) {
        const int row = c_row0 + (mi >> 2) * 64 + (mi & 3) * 16;
#pragma unroll
        for (int n = 0; n < 4; ++n) {
            f32x4 v = acc[mi][n] + bvr[n];
            *(f32x4*)&C[(size_t)row * NDIM + c_col0 + n * 16] = v;
        }
    }
}

extern "C" void kernel_launch(void* const* d_in, const int* in_sizes, int n_in,
                              void* d_out, int out_size, void* d_ws, size_t ws_size,
                              hipStream_t stream) {
    const float* x      = (const float*)d_in[0];
    const float* values = (const float*)d_in[1];
    const float* bias   = (const float*)d_in[2];
    float* out = (float*)d_out;

    // ws: xg bf16 [16384][1024] = 32 MB @ 0; values bf16 [4096][1024] @ 32 MB
    u16* xg = (u16*)d_ws;
    u16* vb = (u16*)((char*)d_ws + ((size_t)32 << 20));

    prep_kernel<<<6144, 256, 0, stream>>>(x, (uint2*)xg, values, (uint4*)vb);
    gemm_kernel<<<1024, 512, 0, stream>>>(xg, vb, bias, out);
}

// Round 11
// 205.482 us; speedup vs baseline: 1.2849x; 1.0541x over previous
//
#include <hip/hip_runtime.h>
#include <hip/hip_bf16.h>

// SrnmSpmm: out[b,s,n] = sum_k x[b,s,keep[k]] * values[n,k] + bias[n]
// keep: cols {8i, 8i+2} of D_IN=4096 -> K=1024. M = B*S = 16384, N = 4096.
//
// R11: R5b skeleton (persistent 256-block, BK=64, 2-deep dbuf, vmcnt(6),
// identical barrier/stage schedule) with 32x32x16 MFMA: half the MFMA
// instructions, +15% pipe rate, 128B store segments. Swizzle extended with
// bit4 <- row-bit-4 (32-row fragments span 2 subtiles) on BOTH the staging
// source and the ds_read address; bank histogram balanced (8-cyc/b128).

#define M_TOTAL 16384
#define DIN     4096
#define KDIM    1024
#define NDIM    4096

typedef unsigned short u16;
typedef unsigned int   u32;
typedef __bf16 bf16x8 __attribute__((ext_vector_type(8)));
typedef float  f32x4  __attribute__((ext_vector_type(4)));
typedef float  f32x16 __attribute__((ext_vector_type(16)));

typedef const void __attribute__((address_space(1)))* gp_t;
typedef void __attribute__((address_space(3)))*       lp_t;

__device__ __forceinline__ u16 f2bf(float f) {
    u32 u = __float_as_uint(f);
    u += 0x7FFFu + ((u >> 16) & 1u);   // round-to-nearest-even
    return (u16)(u >> 16);
}
__device__ __forceinline__ u32 pack2(float a, float b) {
    return (u32)f2bf(a) | ((u32)f2bf(b) << 16);
}

// Pass 1: blocks [0,4096): compact x — each lane owns one 64B line (2 x
// 8-block): f32x4 @ +0 and @ +32B -> uint2 (kept cols 0,2). NT loads.
// Blocks [4096,6144): cast values, 8 floats/lane -> uint4. NT loads.
__global__ void prep_kernel(const float* __restrict__ x, uint2* __restrict__ xg2,
                            const float* __restrict__ vals, uint4* __restrict__ vb4) {
    const int tid = threadIdx.x;
    if (blockIdx.x < 4096) {
        int i = blockIdx.x * 256 + tid;
        const int stride = 4096 * 256;
#pragma unroll
        for (int it = 0; it < 4; ++it, i += stride) {
            const f32x4* p = (const f32x4*)(x + (size_t)i * 16);
            f32x4 f0 = __builtin_nontemporal_load(p);
            f32x4 f1 = __builtin_nontemporal_load(p + 2);
            xg2[i] = make_uint2(pack2(f0.x, f0.z), pack2(f1.x, f1.z));
        }
    } else {
        const int i = (blockIdx.x - 4096) * 256 + tid;
        const f32x4* p = (const f32x4*)(vals + (size_t)i * 8);
        f32x4 a = __builtin_nontemporal_load(p);
        f32x4 b = __builtin_nontemporal_load(p + 1);
        vb4[i] = make_uint4(pack2(a.x, a.y), pack2(a.z, a.w),
                            pack2(b.x, b.y), pack2(b.z, b.w));
    }
}

// ---------------- persistent 256x256 GEMM, 32x32x16 MFMA -------------------
// 512 threads = 8 waves (2M x 4N); wave tile 128x64 = 4m x 2n frags of 32x32.
// K-tile 64 = 2 K-halves (kh) x 2 K-steps (ks=16) each.
// Half-tile slot = 256 rows x 32 cols bf16 = 16 KiB = 2 gload_lds.
// LDS 128 KiB: A[dbuf][kh] @ (2d+kh)*16K, B @ +64K.
// Subtile [16r][32c] = 1 KiB; swizzle: byte ^= (row-bit3)<<5 ^ (row-bit4)<<4,
// applied on the pre-swizzled global SOURCE (gload dest linear) and on the
// ds_read address. Operand layout (32x32x16): row/col = lane&31,
// k = (lane>>5)*8 + j.  C/D: col = lane&31, row = (reg&3)+8*(reg>>2)+4*(lane>>5).

#define LDSA(d, kh) (((d) * 2 + (kh)) * 16384)
#define LDSB(d, kh) (65536 + ((d) * 2 + (kh)) * 16384)

#define LOADA(d, kh, mh) { _Pragma("unroll") \
    for (int mm = 0; mm < 2; ++mm) { _Pragma("unroll") \
    for (int ks = 0; ks < 2; ++ks) \
        af[mm * 2 + ks] = *(const bf16x8*)(lds + LDSA(d, kh) \
            + (wr * 8 + ((mh) * 2 + mm) * 2) * 1024 + fl_base \
            + (((ks << 5) + acol) ^ aswz)); } }

#define LOADB(d, kh) { _Pragma("unroll") \
    for (int nn = 0; nn < 2; ++nn) { _Pragma("unroll") \
    for (int ks = 0; ks < 2; ++ks) \
        bfr[nn * 2 + ks] = *(const bf16x8*)(lds + LDSB(d, kh) \
            + (wc * 4 + nn * 2) * 1024 + fl_base \
            + (((ks << 5) + acol) ^ aswz)); } }

#define MFMA8(mh) { \
    __builtin_amdgcn_s_setprio(1); \
    _Pragma("unroll") for (int mm = 0; mm < 2; ++mm) \
    _Pragma("unroll") for (int nn = 0; nn < 2; ++nn) \
    _Pragma("unroll") for (int ks = 0; ks < 2; ++ks) \
        acc[(mh) * 2 + mm][nn] = __builtin_amdgcn_mfma_f32_32x32x16_bf16( \
            af[mm * 2 + ks], bfr[nn * 2 + ks], acc[(mh) * 2 + mm][nn], 0, 0, 0); \
    __builtin_amdgcn_s_setprio(0); }

#define BAR() __builtin_amdgcn_s_barrier()
#define VMCNT6() asm volatile("s_waitcnt vmcnt(6)" ::: "memory")

__global__ __launch_bounds__(512, 2) void gemm_kernel(
    const u16* __restrict__ A, const u16* __restrict__ Bv,
    const float* __restrict__ bias, float* __restrict__ C)
{
    __shared__ __align__(1024) char lds[131072];

    const int tid  = threadIdx.x;
    const int lane = tid & 63;
    const int wid  = tid >> 6;
    const int wr   = wid >> 2;      // 0..1
    const int wc   = wid & 3;       // 0..3

    // Persistent mapping: XCD (bb&7) covers btm {8c..8c+7}; btn fixed/block.
    const int bb   = blockIdx.x;
    const int btm0 = (bb & 7) * 8 + (bb >> 7);
    const int btn  = (bb >> 3) & 15;

    // Staging source (pre-swizzled global addr; LDS dest linear).
    // Swizzle: elem ^= (tid-bit5 -> 16) ^ (tid-bit6 -> 8)  (byte bits 5,4).
    const int st_r0 = wid * 16 + (lane >> 2);
    const int st_ck = ((lane & 3) * 8) ^ ((tid & 32) >> 1) ^ ((tid & 64) >> 3);
    const u16* A0  = A  + (size_t)(btm0 * 256 + st_r0) * KDIM + st_ck;
    const u16* Bs0 = Bv + (size_t)(btn  * 256 + st_r0) * KDIM + st_ck;
    const int dst0 = tid * 16;

    // Fragment ds_read lane constants (rows = lane&31 span 2 subtiles).
    const int fl_base = (lane & 15) * 64 + ((lane >> 4) & 1) * 1024;
    const int aswz    = (((lane >> 3) & 1) << 5) ^ (((lane >> 4) & 1) << 4);
    const int acol    = ((lane >> 5) & 1) * 16;

    // half-tile slot s: kt=s>>2, j=s&3 (0=A.kh0,1=B.kh0,2=A.kh1,3=B.kh1)
    auto STAGE = [&](const u16* as_, int s) {
        const int kt = s >> 2, j = s & 3;
        const int d = kt & 1, kh = (j >> 1) & 1;
        const int ko = kt * 64 + kh * 32;
        const u16* src = (j & 1) ? Bs0 : as_;
        const int base = ((j & 1) ? 65536 : 0) + (d * 2 + kh) * 16384;
        __builtin_amdgcn_global_load_lds((gp_t)(src + ko),
            (lp_t)(lds + base + dst0), 16, 0, 0);
        __builtin_amdgcn_global_load_lds((gp_t)(src + 128 * KDIM + ko),
            (lp_t)(lds + base + 8192 + dst0), 16, 0, 0);
    };

    // bias (btn fixed): 2 scalars per lane (cols n*32 + lane&31).
    const int c_colb = btn * 256 + wc * 64 + (lane & 31);
    float bvr[2];
#pragma unroll
    for (int n = 0; n < 2; ++n) bvr[n] = bias[c_colb + n * 32];

    f32x16 acc[4][2] = {};
    bf16x8 af[4], bfr[4];

    // Prologue (once): stage K-tile 0 fully + 3 half-tiles of K-tile 1.
    STAGE(A0, 0); STAGE(A0, 1); STAGE(A0, 2); STAGE(A0, 3);
    STAGE(A0, 4); STAGE(A0, 5); STAGE(A0, 6);
    VMCNT6();
    BAR();

#pragma unroll 1
    for (int r = 0; r < 4; ++r) {
        const u16* Ar = A0 + (size_t)r * 512 * KDIM;
        const u16* An = (r < 3) ? (Ar + 512 * KDIM) : Ar;  // r=3: dummy re-stage

#pragma unroll 1
        for (int t = 0; t < 7; ++t) {
            const int s0 = 8 * t + 7;
            // ---- K-tile 2t (dbuf 0) ----
            LOADB(0, 0); LOADA(0, 0, 0); STAGE(Ar, s0);     BAR(); MFMA8(0); BAR();
            LOADA(0, 0, 1);              STAGE(Ar, s0 + 1); BAR(); MFMA8(1); BAR();
            LOADB(0, 1); LOADA(0, 1, 0); STAGE(Ar, s0 + 2); BAR(); MFMA8(0); BAR();
            LOADA(0, 1, 1);              STAGE(Ar, s0 + 3); BAR(); MFMA8(1);
            VMCNT6(); BAR();
            // ---- K-tile 2t+1 (dbuf 1) ----
            LOADB(1, 0); LOADA(1, 0, 0); STAGE(Ar, s0 + 4); BAR(); MFMA8(0); BAR();
            LOADA(1, 0, 1);              STAGE(Ar, s0 + 5); BAR(); MFMA8(1); BAR();
            LOADB(1, 1); LOADA(1, 1, 0); STAGE(Ar, s0 + 6); BAR(); MFMA8(0); BAR();
            LOADA(1, 1, 1);              STAGE(Ar, s0 + 7); BAR(); MFMA8(1);
            VMCNT6(); BAR();
        }
        // ---- tail: K-tiles 14 (dbuf 0) & 15 (dbuf 1); stage slots:
        // s63 (this tile) then n0..n6 (next tile).
        LOADB(0, 0); LOADA(0, 0, 0); STAGE(Ar, 63); BAR(); MFMA8(0); BAR();
        LOADA(0, 0, 1);              STAGE(An, 0);  BAR(); MFMA8(1); BAR();
        LOADB(0, 1); LOADA(0, 1, 0); STAGE(An, 1);  BAR(); MFMA8(0); BAR();
        LOADA(0, 1, 1);              STAGE(An, 2);  BAR(); MFMA8(1);
        VMCNT6(); BAR();
        LOADB(1, 0); LOADA(1, 0, 0); STAGE(An, 3);  BAR(); MFMA8(0); BAR();
        LOADA(1, 0, 1);              STAGE(An, 4);  BAR(); MFMA8(1); BAR();
        LOADB(1, 1); LOADA(1, 1, 0); STAGE(An, 5);  BAR(); MFMA8(0); BAR();
        LOADA(1, 1, 1);              STAGE(An, 6);  BAR(); MFMA8(1);
        VMCNT6(); BAR();

        // Epilogue tile r: NT stores. C/D: col = lane&31 (128B segments),
        // row = mi*32 + (lane>>5)*4 + (q*8) + rr.
        const int c_row0 = (btm0 + 2 * r) * 256 + wr * 128 + ((lane >> 5) & 1) * 4;
#pragma unroll
        for (int mi = 0; mi < 4; ++mi) {
#pragma unroll
            for (int n = 0; n < 2; ++n) {
                f32x16 a = acc[mi][n];
#pragma unroll
                for (int q = 0; q < 4; ++q) {
#pragma unroll
                    for (int rr = 0; rr < 4; ++rr) {
                        const int row = c_row0 + mi * 32 + q * 8 + rr;
                        __builtin_nontemporal_store(a[q * 4 + rr] + bvr[n],
                            &C[(size_t)row * NDIM + c_colb + n * 32]);
                    }
                }
#pragma unroll
                for (int z = 0; z < 16; ++z) acc[mi][n][z] = 0.f;
            }
        }
    }
}

extern "C" void kernel_launch(void* const* d_in, const int* in_sizes, int n_in,
                              void* d_out, int out_size, void* d_ws, size_t ws_size,
                              hipStream_t stream) {
    const float* x      = (const float*)d_in[0];
    const float* values = (const float*)d_in[1];
    const float* bias   = (const float*)d_in[2];
    float* out = (float*)d_out;

    // ws: xg bf16 [16384][1024] = 32 MB @ 0; values bf16 [4096][1024] @ 32 MB
    u16* xg = (u16*)d_ws;
    u16* vb = (u16*)((char*)d_ws + ((size_t)32 << 20));

    prep_kernel<<<6144, 256, 0, stream>>>(x, (uint2*)xg, values, (uint4*)vb);
    gemm_kernel<<<256, 512, 0, stream>>>(xg, vb, bias, out);
}